// Round 1
// 284.205 us; speedup vs baseline: 1.0925x; 1.0925x over previous
//
#include <hip/hip_runtime.h>
#include <cmath>

// Problem constants (fixed by the reference)
constexpr int Bc = 2;
constexpr int Cc = 128;      // input channels
constexpr int Nc = 50000;
constexpr int Hh = 2;        // heads
constexpr int FHc = 64;      // features per head
constexpr int HF = Hh * FHc; // 128 = concat dim
constexpr int Mc = Bc * Nc;  // 100000 nodes
constexpr int Ec = 800000;   // edges

#define NSLOPE_GAT 0.2f
#define NSLOPE_ACT 0.01f
#define LN_EPS 1e-5f
#define SM_EPS 1e-16f
#define LOG2E 1.4426950408889634f

// h-storage is column-swizzled: c' = (c%16)*8 + c/16  (c = canonical col)
// inverse: c = (c'%8)*16 + c'/8. Head of swizzled col c': (c'&7) >= 4.
// => any aligned group of 4 consecutive swizzled cols (one uint2 of bf16)
//    lies entirely within ONE head: head = parity of (c'/4).

typedef __attribute__((ext_vector_type(8))) short short8;
typedef __attribute__((ext_vector_type(4))) float f32x4;

__device__ inline float bf2f_lo(unsigned int u) {
    union { unsigned int i; float f; } v; v.i = u << 16; return v.f;
}
__device__ inline float bf2f_hi(unsigned int u) {
    union { unsigned int i; float f; } v; v.i = u & 0xffff0000u; return v.f;
}
__device__ inline unsigned short f2bf(float f) {
    union { float f; unsigned int i; } v; v.f = f;
    unsigned int r = v.i + 0x7fffu + ((v.i >> 16) & 1u);
    return (unsigned short)(r >> 16);
}

#if __has_builtin(__builtin_amdgcn_exp2f)
#define EXP2(x) __builtin_amdgcn_exp2f(x)
#else
#define EXP2(x) __expf((x) * 0.6931471805599453f)
#endif

// ---------------- K0: W -> B-fragment order (bf16), perm att/bias/gamma/beta,
//                      and zero deg (folded-in former zero_int kernel) -------
// Wb index = ((((mat*8+nt)*4+s)*64)+l)*8 + j ; holds W[k=32s+8*(l>>4)+j][n=16nt+(l&15)]
__global__ __launch_bounds__(256) void prep_w(
    const float* __restrict__ Wl, const float* __restrict__ Wr,
    const float* __restrict__ att, const float* __restrict__ bias,
    const float* __restrict__ gamma, const float* __restrict__ beta,
    unsigned short* __restrict__ Wb, float* __restrict__ att_perm,
    float* __restrict__ bias_perm, float* __restrict__ gamma_perm,
    float* __restrict__ beta_perm, int* __restrict__ deg)
{
    int i = blockIdx.x * 256 + threadIdx.x;
    if (i < Mc) deg[i] = 0;
    if (blockIdx.x == 0 && threadIdx.x < 128) {
        int cp = threadIdx.x;
        int c = (cp & 7) * 16 + (cp >> 3);     // canonical col of swizzled cp
        att_perm[cp]   = att[c] * LOG2E;       // pre-scale: exp(p) == exp2(p*log2e)
        bias_perm[cp]  = bias[c];
        gamma_perm[cp] = gamma[c];
        beta_perm[cp]  = beta[c];
    }
    if (i >= 32768) return;
    int j = i & 7, l = (i >> 3) & 63, s = (i >> 9) & 3, nt = (i >> 11) & 7, mat = (i >> 14) & 1;
    int q = l >> 4, n15 = l & 15;
    int k = 32 * s + 8 * q + j;
    int n = 16 * nt + n15;
    const float* W = mat ? Wr : Wl;
    Wb[i] = f2bf(W[k * HF + n]);
}

// ---------------- K1: MFMA GEMM -> hl, hr bf16, swizzled cols, uint4 stores -
// Also fused: degree count atomics (former deg_kernel). The atomics are
// fire-and-forget and overlap with LDS staging + MFMA.
__global__ __launch_bounds__(256) void gemm_hlr_mfma(
    const float* __restrict__ x,
    const unsigned short* __restrict__ Wb,
    const float* __restrict__ bl, const float* __restrict__ br,
    const int* __restrict__ ei, int* __restrict__ deg,
    unsigned short* __restrict__ hl, unsigned short* __restrict__ hr)
{
    // fused degree count: 400128 threads x 2 edges covers Ec=800000
    {
        int gtid = blockIdx.x * 256 + threadIdx.x;
        int e = gtid * 2;
        if (e < Ec)     atomicAdd(&deg[ei[Ec + e]], 1);
        if (e + 1 < Ec) atomicAdd(&deg[ei[Ec + e + 1]], 1);
    }

    __shared__ float xsT[Cc][65]; // [c][row], stride 65 dwords -> <=2-way conflicts (free)
    const int r0 = blockIdx.x * 64;
    const int tid = threadIdx.x;

    #pragma unroll
    for (int pass = 0; pass < 8; ++pass) {
        int idx = pass * 256 + tid;
        int c = idx >> 4, rf = (idx & 15) * 4;
        int r = r0 + rf;
        if (r + 3 < Mc) { // 4-aligned groups never straddle the b=0/1 boundary (50000%4==0)
            int b = r / Nc, n = r - b * Nc;
            float4 v = *(const float4*)(x + (size_t)(b * Cc + c) * Nc + n);
            xsT[c][rf + 0] = v.x; xsT[c][rf + 1] = v.y;
            xsT[c][rf + 2] = v.z; xsT[c][rf + 3] = v.w;
        } else {
            #pragma unroll
            for (int i = 0; i < 4; ++i) {
                int rr = r + i; float vv = 0.f;
                if (rr < Mc) { int bb = rr / Nc, nn = rr - bb * Nc; vv = x[(size_t)(bb * Cc + c) * Nc + nn]; }
                xsT[c][rf + i] = vv;
            }
        }
    }
    __syncthreads();

    const int l = tid & 63, w = tid >> 6;
    const int m15 = l & 15, q = l >> 4;
    const int rowA = 16 * w + m15;

    short8 afrag[4];
    #pragma unroll
    for (int s = 0; s < 4; ++s) {
        short8 t;
        #pragma unroll
        for (int j = 0; j < 8; ++j)
            t[j] = (short)f2bf(xsT[32 * s + 8 * q + j][rowA]);
        afrag[s] = t;
    }

    f32x4 accl[8], accr[8];
    #pragma unroll
    for (int nt = 0; nt < 8; ++nt) {
        accl[nt] = (f32x4)(0.f);
        accr[nt] = (f32x4)(0.f);
    }

    const short8* __restrict__ WB = (const short8*)Wb;
    #pragma unroll
    for (int s = 0; s < 4; ++s) {
        #pragma unroll
        for (int nt = 0; nt < 8; ++nt) {
            short8 b0 = WB[((0 * 8 + nt) * 4 + s) * 64 + l];
            short8 b1 = WB[((1 * 8 + nt) * 4 + s) * 64 + l];
            accl[nt] = __builtin_amdgcn_mfma_f32_16x16x32_bf16(afrag[s], b0, accl[nt], 0, 0, 0);
            accr[nt] = __builtin_amdgcn_mfma_f32_16x16x32_bf16(afrag[s], b1, accr[nt], 0, 0, 0);
        }
    }

    // epilogue: D row = (l>>4)*4+reg, canonical col = 16nt+m15 -> swizzled col'
    // = m15*8+nt: lane's 8 values per row are CONTIGUOUS -> one uint4 store.
    float bLv[8], bRv[8];
    #pragma unroll
    for (int nt = 0; nt < 8; ++nt) {
        bLv[nt] = bl[16 * nt + m15];
        bRv[nt] = br[16 * nt + m15];
    }
    const int rowD0 = r0 + 16 * w + 4 * q;
    #pragma unroll
    for (int reg = 0; reg < 4; ++reg) {
        int r = rowD0 + reg;
        if (r < Mc) {
            uint4 ul, ur;
            unsigned int* pl = (unsigned int*)&ul;
            unsigned int* pr = (unsigned int*)&ur;
            #pragma unroll
            for (int dw = 0; dw < 4; ++dw) {
                unsigned int lo = f2bf(accl[2 * dw][reg] + bLv[2 * dw]);
                unsigned int hi = f2bf(accl[2 * dw + 1][reg] + bLv[2 * dw + 1]);
                pl[dw] = lo | (hi << 16);
                unsigned int lo2 = f2bf(accr[2 * dw][reg] + bRv[2 * dw]);
                unsigned int hi2 = f2bf(accr[2 * dw + 1][reg] + bRv[2 * dw + 1]);
                pr[dw] = lo2 | (hi2 << 16);
            }
            *(uint4*)(hl + (size_t)r * HF + m15 * 8) = ul;
            *(uint4*)(hr + (size_t)r * HF + m15 * 8) = ur;
        }
    }
}

// ---------------- CSR build (scan + scatter; zero/deg are fused away) -------
__global__ __launch_bounds__(256) void scan_block(const int* __restrict__ deg,
                                                  int* __restrict__ offs,
                                                  int* __restrict__ partials, int M)
{
    __shared__ int sdata[256];
    const int base = blockIdx.x * 1024;
    const int tid = threadIdx.x;
    int v[4];
    int tsum = 0;
    #pragma unroll
    for (int j = 0; j < 4; ++j) {
        int idx = base + tid * 4 + j;
        v[j] = (idx < M) ? deg[idx] : 0;
        tsum += v[j];
    }
    sdata[tid] = tsum;
    __syncthreads();
    for (int off = 1; off < 256; off <<= 1) {
        int xv = (tid >= off) ? sdata[tid - off] : 0;
        __syncthreads();
        sdata[tid] += xv;
        __syncthreads();
    }
    int run = sdata[tid] - tsum;
    #pragma unroll
    for (int j = 0; j < 4; ++j) {
        int idx = base + tid * 4 + j;
        if (idx < M) offs[idx] = run;
        run += v[j];
    }
    if (tid == 255) partials[blockIdx.x] = sdata[255];
}

__global__ __launch_bounds__(128) void scan_partials(int* __restrict__ partials, int nb) {
    __shared__ int sd[128];
    int tid = threadIdx.x;
    int v = (tid < nb) ? partials[tid] : 0;
    sd[tid] = v;
    __syncthreads();
    for (int off = 1; off < 128; off <<= 1) {
        int xv = (tid >= off) ? sd[tid - off] : 0;
        __syncthreads();
        sd[tid] += xv;
        __syncthreads();
    }
    if (tid < nb) partials[tid] = sd[tid] - v;
}

__global__ void add_offsets(int* __restrict__ offs, int* __restrict__ cursor,
                            const int* __restrict__ partials, int M) {
    int idx = blockIdx.x * 256 + threadIdx.x;
    if (idx < M) {
        int o = offs[idx] + partials[idx >> 10];
        offs[idx] = o;
        cursor[idx] = o;
    }
}

__global__ void scatter_edges(const int* __restrict__ ei, int* __restrict__ cursor,
                              int* __restrict__ csr_src, int E) {
    int e = blockIdx.x * 256 + threadIdx.x;
    if (e < E) {
        int s = ei[e];
        int d = ei[E + e];
        int p = atomicAdd(&cursor[d], 1);
        csr_src[p] = s;
    }
}

// ---------------- K4: fully fused per-node logits+softmax+aggregate+LN ------
// One wave per node, TWO edges per iteration (one per 32-lane half).
// Lane t: half = t>>5 (edge select), i32 = t&31. Lane holds swizzled cols
// 4*i32..4*i32+3 (one uint2 of bf16) -- all in head (i32&1) by the swizzle
// property. Per-head dot = 4 in-lane FMAs + 4-step xor butterfly over masks
// {2,4,8,16}: bit0 (head) and bit5 (half) untouched -> each lane sums exactly
// its head's 16 lanes of its half. All shuffles are within-32 => cheap
// ds_swizzle, no cross-32 bpermute in the inner loop. att is pre-scaled by
// log2e so the weight is a bare v_exp_f32. Halves merge once per node.
__global__ __launch_bounds__(256) void gat_fused(
    const unsigned short* __restrict__ hl, const unsigned short* __restrict__ hr,
    const int* __restrict__ csr_src,
    const int* __restrict__ offs, const int* __restrict__ deg,
    const float* __restrict__ att_perm, const float* __restrict__ bias_perm,
    const float* __restrict__ gamma_perm, const float* __restrict__ beta_perm,
    float* __restrict__ out)
{
    const int wv = threadIdx.x >> 6;
    const int t  = threadIdx.x & 63;
    const int d  = blockIdx.x * 4 + wv;
    if (d >= Mc) return;
    const int off = __builtin_amdgcn_readfirstlane(offs[d]);
    const int n   = __builtin_amdgcn_readfirstlane(deg[d]);
    const int i32 = t & 31;
    const bool hiHalf = (t >= 32);
    const unsigned int voff = 8u * (unsigned)i32; // byte offset within a 256B row

    const uint2 ur = *(const uint2*)(hr + (size_t)d * HF + 4 * i32);
    const float hr0 = bf2f_lo(ur.x), hr1 = bf2f_hi(ur.x);
    const float hr2 = bf2f_lo(ur.y), hr3 = bf2f_hi(ur.y);
    const float4 ap = *(const float4*)(att_perm + 4 * i32);

    float l = 0.f, acc0 = 0.f, acc1 = 0.f, acc2 = 0.f, acc3 = 0.f;
    const char* __restrict__ hlb = (const char*)hl;

    auto pair = [&](int sa, int sb, bool tailMask) {
        int s = hiHalf ? sb : sa;
        unsigned int boff = ((unsigned int)s << 8) + voff;
        const uint2 u = *(const uint2*)(hlb + boff);
        float a0 = bf2f_lo(u.x), a1 = bf2f_hi(u.x);
        float a2 = bf2f_lo(u.y), a3 = bf2f_hi(u.y);
        float z0 = a0 + hr0, z1 = a1 + hr1, z2 = a2 + hr2, z3 = a3 + hr3;
        // leaky_relu(z) == max(z, slope*z) for 0<slope<1
        z0 = fmaxf(z0, NSLOPE_GAT * z0);
        z1 = fmaxf(z1, NSLOPE_GAT * z1);
        z2 = fmaxf(z2, NSLOPE_GAT * z2);
        z3 = fmaxf(z3, NSLOPE_GAT * z3);
        float p = fmaf(z0, ap.x, z1 * ap.y) + fmaf(z2, ap.z, z3 * ap.w);
        p += __shfl_xor(p, 2, 64);
        p += __shfl_xor(p, 4, 64);
        p += __shfl_xor(p, 8, 64);
        p += __shfl_xor(p, 16, 64);
        float w = EXP2(p);               // att pre-scaled by log2e
        if (tailMask && hiHalf) w = 0.f; // odd-degree tail: high half is a dup
        l += w;
        acc0 = fmaf(w, a0, acc0);
        acc1 = fmaf(w, a1, acc1);
        acc2 = fmaf(w, a2, acc2);
        acc3 = fmaf(w, a3, acc3);
    };

    int i = 0;
    for (; i + 4 <= n; i += 4) {
        int s0 = csr_src[off + i];
        int s1 = csr_src[off + i + 1];
        int s2 = csr_src[off + i + 2];
        int s3 = csr_src[off + i + 3];
        pair(s0, s1, false);
        pair(s2, s3, false);
    }
    if (i + 2 <= n) {
        int s0 = csr_src[off + i];
        int s1 = csr_src[off + i + 1];
        pair(s0, s1, false);
        i += 2;
    }
    if (i < n) {
        int s0 = csr_src[off + i];
        pair(s0, s0, true);
    }

    // merge the two edge-halves (same swizzled cols in both halves)
    l    += __shfl_xor(l, 32, 64);
    acc0 += __shfl_xor(acc0, 32, 64);
    acc1 += __shfl_xor(acc1, 32, 64);
    acc2 += __shfl_xor(acc2, 32, 64);
    acc3 += __shfl_xor(acc3, 32, 64);

    float inv = 1.f / (l + SM_EPS);
    const float4 bp = *(const float4*)(bias_perm + 4 * i32);
    float v0 = fmaf(acc0, inv, bp.x);
    float v1 = fmaf(acc1, inv, bp.y);
    float v2 = fmaf(acc2, inv, bp.z);
    float v3 = fmaf(acc3, inv, bp.w);

    // LayerNorm over 128 features: each 32-lane half holds all 128 exactly
    // once (4 per lane) -> 5-step butterfly within the half.
    float sum = (v0 + v1) + (v2 + v3);
    #pragma unroll
    for (int o = 1; o <= 16; o <<= 1) sum += __shfl_xor(sum, o, 64);
    float mu = sum * (1.f / 128.f);
    float d0 = v0 - mu, d1 = v1 - mu, d2 = v2 - mu, d3 = v3 - mu;
    float sq = (d0 * d0 + d1 * d1) + (d2 * d2 + d3 * d3);
    #pragma unroll
    for (int o = 1; o <= 16; o <<= 1) sq += __shfl_xor(sq, o, 64);
    float rstd = rsqrtf(sq * (1.f / 128.f) + LN_EPS);

    const float4 g  = *(const float4*)(gamma_perm + 4 * i32);
    const float4 be = *(const float4*)(beta_perm + 4 * i32);
    float y0 = fmaf(d0 * rstd, g.x, be.x);
    float y1 = fmaf(d1 * rstd, g.y, be.y);
    float y2 = fmaf(d2 * rstd, g.z, be.z);
    float y3 = fmaf(d3 * rstd, g.w, be.w);
    y0 = fmaxf(y0, NSLOPE_ACT * y0);
    y1 = fmaxf(y1, NSLOPE_ACT * y1);
    y2 = fmaxf(y2, NSLOPE_ACT * y2);
    y3 = fmaxf(y3, NSLOPE_ACT * y3);

    // canonical col of slot j: c = 64*(i32&1) + 16*j + (i32>>1)
    if (!hiHalf) {
        const int h = i32 & 1, m = i32 >> 1;
        float* op = out + (size_t)d * HF + 64 * h + m;
        op[0]  = y0;
        op[16] = y1;
        op[32] = y2;
        op[48] = y3;
    }
}

// ---------------- launch ----------------
extern "C" void kernel_launch(void* const* d_in, const int* in_sizes, int n_in,
                              void* d_out, int out_size, void* d_ws, size_t ws_size,
                              hipStream_t stream) {
    const float* x     = (const float*)d_in[0];
    const int*   ei    = (const int*)d_in[1];
    const float* Wl    = (const float*)d_in[2];
    const float* bl    = (const float*)d_in[3];
    const float* Wr    = (const float*)d_in[4];
    const float* br    = (const float*)d_in[5];
    const float* att   = (const float*)d_in[6];
    const float* bias  = (const float*)d_in[7];
    const float* gamma = (const float*)d_in[8];
    const float* beta  = (const float*)d_in[9];
    float* out = (float*)d_out;

    char* ws = (char*)d_ws;
    unsigned short* hl = (unsigned short*)ws; ws += (size_t)Mc * HF * 2; // 25.6 MB
    unsigned short* hr = (unsigned short*)ws; ws += (size_t)Mc * HF * 2; // 25.6 MB
    unsigned short* Wb = (unsigned short*)ws; ws += 32768 * 2;           // 64 KB
    float* att_perm   = (float*)ws; ws += 128 * sizeof(float);
    float* bias_perm  = (float*)ws; ws += 128 * sizeof(float);
    float* gamma_perm = (float*)ws; ws += 128 * sizeof(float);
    float* beta_perm  = (float*)ws; ws += 128 * sizeof(float);
    int* deg = (int*)ws;         ws += (size_t)Mc * sizeof(int);
    int* offs = (int*)ws;        ws += (size_t)Mc * sizeof(int);
    int* cursor = (int*)ws;      ws += (size_t)Mc * sizeof(int);
    int* partials = (int*)ws;    ws += 512;
    int* csr_src = (int*)ws;     ws += (size_t)Ec * sizeof(int);

    const int nb = (Mc + 1023) / 1024; // 98 <= 128

    // prep_w also zeros deg; gemm also counts degrees (stream order: zero ->
    // count -> scan is preserved across dispatch boundaries).
    prep_w<<<(Mc + 255) / 256, 256, 0, stream>>>(Wl, Wr, att, bias, gamma, beta,
                                                 Wb, att_perm, bias_perm,
                                                 gamma_perm, beta_perm, deg);
    gemm_hlr_mfma<<<(Mc + 63) / 64, 256, 0, stream>>>(x, Wb, bl, br, ei, deg, hl, hr);

    scan_block<<<nb, 256, 0, stream>>>(deg, offs, partials, Mc);
    scan_partials<<<1, 128, 0, stream>>>(partials, nb);
    add_offsets<<<(Mc + 255) / 256, 256, 0, stream>>>(offs, cursor, partials, Mc);
    scatter_edges<<<(Ec + 255) / 256, 256, 0, stream>>>(ei, cursor, csr_src, Ec);

    gat_fused<<<(Mc + 3) / 4, 256, 0, stream>>>(hl, hr, csr_src, offs, deg,
                                                att_perm, bias_perm, gamma_perm,
                                                beta_perm, out);
}

// Round 2
// 277.184 us; speedup vs baseline: 1.1202x; 1.0253x over previous
//
#include <hip/hip_runtime.h>
#include <cmath>

// Problem constants (fixed by the reference)
constexpr int Bc = 2;
constexpr int Cc = 128;      // input channels
constexpr int Nc = 50000;
constexpr int Hh = 2;        // heads
constexpr int FHc = 64;      // features per head
constexpr int HF = Hh * FHc; // 128 = concat dim
constexpr int Mc = Bc * Nc;  // 100000 nodes
constexpr int Ec = 800000;   // edges

#define NSLOPE_GAT 0.2f
#define NSLOPE_ACT 0.01f
#define LN_EPS 1e-5f
#define SM_EPS 1e-16f
#define LOG2E 1.4426950408889634f

// h-storage is column-swizzled: c' = (c%16)*8 + c/16  (c = canonical col)
// inverse: c = (c'%8)*16 + c'/8. Head of swizzled col c': (c'&7) >= 4.
// => any aligned group of 4 consecutive swizzled cols (one uint2 of bf16)
//    lies entirely within ONE head: head = parity of (c'/4).

typedef __attribute__((ext_vector_type(8))) short short8;
typedef __attribute__((ext_vector_type(4))) float f32x4;

__device__ inline float bf2f_lo(unsigned int u) {
    union { unsigned int i; float f; } v; v.i = u << 16; return v.f;
}
__device__ inline float bf2f_hi(unsigned int u) {
    union { unsigned int i; float f; } v; v.i = u & 0xffff0000u; return v.f;
}
__device__ inline unsigned short f2bf(float f) {
    union { float f; unsigned int i; } v; v.f = f;
    unsigned int r = v.i + 0x7fffu + ((v.i >> 16) & 1u);
    return (unsigned short)(r >> 16);
}

#if __has_builtin(__builtin_amdgcn_exp2f)
#define EXP2(x) __builtin_amdgcn_exp2f(x)
#else
#define EXP2(x) __expf((x) * 0.6931471805599453f)
#endif

// ---------------- K0: W -> B-fragment order (bf16), perm att/bias/gamma/beta,
//                      and zero deg --------------------------------------
// Wb index = ((((mat*8+nt)*4+s)*64)+l)*8 + j ; holds W[k=32s+8*(l>>4)+j][n=16nt+(l&15)]
__global__ __launch_bounds__(256) void prep_w(
    const float* __restrict__ Wl, const float* __restrict__ Wr,
    const float* __restrict__ att, const float* __restrict__ bias,
    const float* __restrict__ gamma, const float* __restrict__ beta,
    unsigned short* __restrict__ Wb, float* __restrict__ att_perm,
    float* __restrict__ bias_perm, float* __restrict__ gamma_perm,
    float* __restrict__ beta_perm, int* __restrict__ deg)
{
    int i = blockIdx.x * 256 + threadIdx.x;
    if (i < Mc) deg[i] = 0;
    if (blockIdx.x == 0 && threadIdx.x < 128) {
        int cp = threadIdx.x;
        int c = (cp & 7) * 16 + (cp >> 3);     // canonical col of swizzled cp
        att_perm[cp]   = att[c] * LOG2E;       // pre-scale: exp(p) == exp2(p*log2e)
        bias_perm[cp]  = bias[c];
        gamma_perm[cp] = gamma[c];
        beta_perm[cp]  = beta[c];
    }
    if (i >= 32768) return;
    int j = i & 7, l = (i >> 3) & 63, s = (i >> 9) & 3, nt = (i >> 11) & 7, mat = (i >> 14) & 1;
    int q = l >> 4, n15 = l & 15;
    int k = 32 * s + 8 * q + j;
    int n = 16 * nt + n15;
    const float* W = mat ? Wr : Wl;
    Wb[i] = f2bf(W[k * HF + n]);
}

// ---------------- degree count (standalone: no barrier behind the atomics) --
__global__ __launch_bounds__(256) void deg_kernel(const int* __restrict__ ei,
                                                  int* __restrict__ deg) {
    int g = blockIdx.x * 256 + threadIdx.x;
    int e = g * 2;
    if (e + 1 < Ec) {
        int2 dd = *(const int2*)(ei + Ec + e);
        atomicAdd(&deg[dd.x], 1);
        atomicAdd(&deg[dd.y], 1);
    } else if (e < Ec) {
        atomicAdd(&deg[ei[Ec + e]], 1);
    }
}

// ---------------- K1: MFMA GEMM -> hl, hr bf16, swizzled cols ---------------
// 64-row M-tile, 4 waves. Wave w owns matrix (w>>1), nt columns 4*(w&1)..+3:
// its 16 B-fragments load from global ONCE into 64 VGPRs -- the MFMA loop
// touches only LDS + registers. A-tile staged as bf16 [row][k] with
// byte ^= (row&7)<<4 XOR swizzle: A-fragments are single conflict-free
// ds_read_b128; staging writes (lane=row) also spread across banks.
__global__ __launch_bounds__(256, 3) void gemm_hlr_mfma(
    const float* __restrict__ x,
    const unsigned short* __restrict__ Wb,
    const float* __restrict__ bl, const float* __restrict__ br,
    unsigned short* __restrict__ hl, unsigned short* __restrict__ hr)
{
    __shared__ unsigned char As[64 * 256]; // 16 KB: [row][2*k] bf16, swizzled
    const int tid = threadIdx.x;
    const int r0 = blockIdx.x * 64;
    const int l = tid & 63, w = tid >> 6;
    const int m15 = l & 15, q = l >> 4;

    // --- B fragments: 16 per wave, global->VGPR once (L2-hot, 64 KB total)
    const int matw = w >> 1, ntb = 4 * (w & 1);
    const short8* __restrict__ WB = (const short8*)Wb;
    short8 bfrag[4][4]; // [i = nt offset][s = k-step]
    #pragma unroll
    for (int i = 0; i < 4; ++i)
        #pragma unroll
        for (int s = 0; s < 4; ++s)
            bfrag[i][s] = WB[(((matw * 8 + ntb + i) * 4 + s) * 64) + l];

    // --- stage A: lane = row, 4 channels/thread/pass, dword loads
    {
        const int lrow = tid & 63;          // local row
        const int cg   = (tid >> 6) * 4;    // channel group base
        const int grow = r0 + lrow;
        const unsigned int swz = (unsigned)((lrow & 7) << 4);
        const bool valid = grow < Mc;
        int b = 0, n = grow;
        if (n >= Nc) { b = 1; n -= Nc; }
        const float* xb = x + (size_t)(b * Cc) * Nc + n;
        #pragma unroll
        for (int p = 0; p < 8; ++p) {
            int c = cg + 16 * p;
            float v0 = 0.f, v1 = 0.f, v2 = 0.f, v3 = 0.f;
            if (valid) {
                const float* xp = xb + (size_t)c * Nc;
                v0 = xp[0];
                v1 = xp[Nc];
                v2 = xp[2 * (size_t)Nc];
                v3 = xp[3 * (size_t)Nc];
            }
            unsigned int d0 = (unsigned)f2bf(v0) | ((unsigned)f2bf(v1) << 16);
            unsigned int d1 = (unsigned)f2bf(v2) | ((unsigned)f2bf(v3) << 16);
            unsigned int off = (unsigned)lrow * 256 + (((unsigned)(c * 2)) ^ swz);
            *(uint2*)(As + off) = make_uint2(d0, d1);
        }
    }
    __syncthreads();

    // --- bias (canonical col = 16*nt + m15) and output base
    const float* bsrc = matw ? br : bl;
    unsigned short* __restrict__ hdst = matw ? hr : hl;
    float bv[4];
    #pragma unroll
    for (int i = 0; i < 4; ++i) bv[i] = bsrc[16 * (ntb + i) + m15];

    const unsigned int rswz = (unsigned)((m15 & 7) << 4);
    #pragma unroll
    for (int mt = 0; mt < 4; ++mt) {
        short8 af[4];
        #pragma unroll
        for (int s = 0; s < 4; ++s) {
            unsigned int off = (unsigned)(16 * mt + m15) * 256 +
                               (((unsigned)(64 * s + 16 * q)) ^ rswz);
            af[s] = *(const short8*)(As + off);
        }
        f32x4 acc[4];
        #pragma unroll
        for (int i = 0; i < 4; ++i) acc[i] = (f32x4)(0.f);
        #pragma unroll
        for (int s = 0; s < 4; ++s)
            #pragma unroll
            for (int i = 0; i < 4; ++i)
                acc[i] = __builtin_amdgcn_mfma_f32_16x16x32_bf16(af[s], bfrag[i][s], acc[i], 0, 0, 0);

        // D: row = 4q+reg (tile-local), canonical col = 16*(ntb+i)+m15
        // swizzled col' = m15*8 + ntb + i  ->  uint2 (4 bf16) per row
        #pragma unroll
        for (int reg = 0; reg < 4; ++reg) {
            int rD = r0 + 16 * mt + 4 * q + reg;
            if (rD < Mc) {
                unsigned int lo = (unsigned)f2bf(acc[0][reg] + bv[0]) |
                                  ((unsigned)f2bf(acc[1][reg] + bv[1]) << 16);
                unsigned int hi = (unsigned)f2bf(acc[2][reg] + bv[2]) |
                                  ((unsigned)f2bf(acc[3][reg] + bv[3]) << 16);
                *(uint2*)(hdst + (size_t)rD * HF + m15 * 8 + ntb) = make_uint2(lo, hi);
            }
        }
    }
}

// ---------------- CSR build -------------------------------------------------
__global__ __launch_bounds__(256) void scan_block(const int* __restrict__ deg,
                                                  int* __restrict__ offs,
                                                  int* __restrict__ partials, int M)
{
    __shared__ int sdata[256];
    const int base = blockIdx.x * 1024;
    const int tid = threadIdx.x;
    int v[4];
    int tsum = 0;
    #pragma unroll
    for (int j = 0; j < 4; ++j) {
        int idx = base + tid * 4 + j;
        v[j] = (idx < M) ? deg[idx] : 0;
        tsum += v[j];
    }
    sdata[tid] = tsum;
    __syncthreads();
    for (int off = 1; off < 256; off <<= 1) {
        int xv = (tid >= off) ? sdata[tid - off] : 0;
        __syncthreads();
        sdata[tid] += xv;
        __syncthreads();
    }
    int run = sdata[tid] - tsum;
    #pragma unroll
    for (int j = 0; j < 4; ++j) {
        int idx = base + tid * 4 + j;
        if (idx < M) offs[idx] = run;
        run += v[j];
    }
    if (tid == 255) partials[blockIdx.x] = sdata[255]; // RAW block sums
}

// Each block covers idx in [blk*256, blk*256+256) -> one 1024-chunk
// (chunk = blk>>2), so it just needs sum(partials[0..chunk-1]).
__global__ __launch_bounds__(256) void add_offsets(int* __restrict__ offs,
                                                   int* __restrict__ cursor,
                                                   const int* __restrict__ partials,
                                                   int M) {
    __shared__ int sw[4];
    const int chunk = blockIdx.x >> 2;
    const int t = threadIdx.x;
    int v = (t < chunk) ? partials[t] : 0; // chunk <= 97 < 256
    #pragma unroll
    for (int o = 32; o; o >>= 1) v += __shfl_xor(v, o, 64);
    if ((t & 63) == 0) sw[t >> 6] = v;
    __syncthreads();
    int base = sw[0] + sw[1] + sw[2] + sw[3];
    int idx = blockIdx.x * 256 + t;
    if (idx < M) {
        int o = offs[idx] + base;
        offs[idx] = o;
        cursor[idx] = o;
    }
}

__global__ void scatter_edges(const int* __restrict__ ei, int* __restrict__ cursor,
                              int* __restrict__ csr_src, int E) {
    int e = blockIdx.x * 256 + threadIdx.x;
    if (e < E) {
        int s = ei[e];
        int d = ei[E + e];
        int p = atomicAdd(&cursor[d], 1);
        csr_src[p] = s;
    }
}

// ---------------- K4: fully fused per-node logits+softmax+aggregate+LN ------
// One wave per node, TWO edges per iteration (one per 32-lane half).
// Lane t: half = t>>5 (edge select), i32 = t&31. Lane holds swizzled cols
// 4*i32..4*i32+3 (one uint2 of bf16) -- all in head (i32&1) by the swizzle
// property. Per-head dot = 4 in-lane FMAs + 4-step xor butterfly over masks
// {2,4,8,16}: all within-32 => cheap ds_swizzle. att pre-scaled by log2e so
// the weight is a bare v_exp_f32. Halves merge once per node.
__global__ __launch_bounds__(256) void gat_fused(
    const unsigned short* __restrict__ hl, const unsigned short* __restrict__ hr,
    const int* __restrict__ csr_src,
    const int* __restrict__ offs, const int* __restrict__ deg,
    const float* __restrict__ att_perm, const float* __restrict__ bias_perm,
    const float* __restrict__ gamma_perm, const float* __restrict__ beta_perm,
    float* __restrict__ out)
{
    const int wv = threadIdx.x >> 6;
    const int t  = threadIdx.x & 63;
    const int d  = blockIdx.x * 4 + wv;
    if (d >= Mc) return;
    const int off = __builtin_amdgcn_readfirstlane(offs[d]);
    const int n   = __builtin_amdgcn_readfirstlane(deg[d]);
    const int i32 = t & 31;
    const bool hiHalf = (t >= 32);
    const unsigned int voff = 8u * (unsigned)i32; // byte offset within a 256B row

    const uint2 ur = *(const uint2*)(hr + (size_t)d * HF + 4 * i32);
    const float hr0 = bf2f_lo(ur.x), hr1 = bf2f_hi(ur.x);
    const float hr2 = bf2f_lo(ur.y), hr3 = bf2f_hi(ur.y);
    const float4 ap = *(const float4*)(att_perm + 4 * i32);

    float l = 0.f, acc0 = 0.f, acc1 = 0.f, acc2 = 0.f, acc3 = 0.f;
    const char* __restrict__ hlb = (const char*)hl;

    auto pair = [&](int sa, int sb, bool tailMask) {
        int s = hiHalf ? sb : sa;
        unsigned int boff = ((unsigned int)s << 8) + voff;
        const uint2 u = *(const uint2*)(hlb + boff);
        float a0 = bf2f_lo(u.x), a1 = bf2f_hi(u.x);
        float a2 = bf2f_lo(u.y), a3 = bf2f_hi(u.y);
        float z0 = a0 + hr0, z1 = a1 + hr1, z2 = a2 + hr2, z3 = a3 + hr3;
        z0 = fmaxf(z0, NSLOPE_GAT * z0);
        z1 = fmaxf(z1, NSLOPE_GAT * z1);
        z2 = fmaxf(z2, NSLOPE_GAT * z2);
        z3 = fmaxf(z3, NSLOPE_GAT * z3);
        float p = fmaf(z0, ap.x, z1 * ap.y) + fmaf(z2, ap.z, z3 * ap.w);
        p += __shfl_xor(p, 2, 64);
        p += __shfl_xor(p, 4, 64);
        p += __shfl_xor(p, 8, 64);
        p += __shfl_xor(p, 16, 64);
        float w = EXP2(p);               // att pre-scaled by log2e
        if (tailMask && hiHalf) w = 0.f; // odd-degree tail: high half is a dup
        l += w;
        acc0 = fmaf(w, a0, acc0);
        acc1 = fmaf(w, a1, acc1);
        acc2 = fmaf(w, a2, acc2);
        acc3 = fmaf(w, a3, acc3);
    };

    int i = 0;
    for (; i + 4 <= n; i += 4) {
        int s0 = csr_src[off + i];
        int s1 = csr_src[off + i + 1];
        int s2 = csr_src[off + i + 2];
        int s3 = csr_src[off + i + 3];
        pair(s0, s1, false);
        pair(s2, s3, false);
    }
    if (i + 2 <= n) {
        int s0 = csr_src[off + i];
        int s1 = csr_src[off + i + 1];
        pair(s0, s1, false);
        i += 2;
    }
    if (i < n) {
        int s0 = csr_src[off + i];
        pair(s0, s0, true);
    }

    // merge the two edge-halves (same swizzled cols in both halves)
    l    += __shfl_xor(l, 32, 64);
    acc0 += __shfl_xor(acc0, 32, 64);
    acc1 += __shfl_xor(acc1, 32, 64);
    acc2 += __shfl_xor(acc2, 32, 64);
    acc3 += __shfl_xor(acc3, 32, 64);

    float inv = 1.f / (l + SM_EPS);
    const float4 bp = *(const float4*)(bias_perm + 4 * i32);
    float v0 = fmaf(acc0, inv, bp.x);
    float v1 = fmaf(acc1, inv, bp.y);
    float v2 = fmaf(acc2, inv, bp.z);
    float v3 = fmaf(acc3, inv, bp.w);

    // LayerNorm over 128 features: each 32-lane half holds all 128 exactly once
    float sum = (v0 + v1) + (v2 + v3);
    #pragma unroll
    for (int o = 1; o <= 16; o <<= 1) sum += __shfl_xor(sum, o, 64);
    float mu = sum * (1.f / 128.f);
    float d0 = v0 - mu, d1 = v1 - mu, d2 = v2 - mu, d3 = v3 - mu;
    float sq = (d0 * d0 + d1 * d1) + (d2 * d2 + d3 * d3);
    #pragma unroll
    for (int o = 1; o <= 16; o <<= 1) sq += __shfl_xor(sq, o, 64);
    float rstd = rsqrtf(sq * (1.f / 128.f) + LN_EPS);

    const float4 g  = *(const float4*)(gamma_perm + 4 * i32);
    const float4 be = *(const float4*)(beta_perm + 4 * i32);
    float y0 = fmaf(d0 * rstd, g.x, be.x);
    float y1 = fmaf(d1 * rstd, g.y, be.y);
    float y2 = fmaf(d2 * rstd, g.z, be.z);
    float y3 = fmaf(d3 * rstd, g.w, be.w);
    y0 = fmaxf(y0, NSLOPE_ACT * y0);
    y1 = fmaxf(y1, NSLOPE_ACT * y1);
    y2 = fmaxf(y2, NSLOPE_ACT * y2);
    y3 = fmaxf(y3, NSLOPE_ACT * y3);

    // canonical col of slot j: c = 64*(i32&1) + 16*j + (i32>>1)
    if (!hiHalf) {
        const int h = i32 & 1, m = i32 >> 1;
        float* op = out + (size_t)d * HF + 64 * h + m;
        op[0]  = y0;
        op[16] = y1;
        op[32] = y2;
        op[48] = y3;
    }
}

// ---------------- launch ----------------
extern "C" void kernel_launch(void* const* d_in, const int* in_sizes, int n_in,
                              void* d_out, int out_size, void* d_ws, size_t ws_size,
                              hipStream_t stream) {
    const float* x     = (const float*)d_in[0];
    const int*   ei    = (const int*)d_in[1];
    const float* Wl    = (const float*)d_in[2];
    const float* bl    = (const float*)d_in[3];
    const float* Wr    = (const float*)d_in[4];
    const float* br    = (const float*)d_in[5];
    const float* att   = (const float*)d_in[6];
    const float* bias  = (const float*)d_in[7];
    const float* gamma = (const float*)d_in[8];
    const float* beta  = (const float*)d_in[9];
    float* out = (float*)d_out;

    char* ws = (char*)d_ws;
    unsigned short* hl = (unsigned short*)ws; ws += (size_t)Mc * HF * 2; // 25.6 MB
    unsigned short* hr = (unsigned short*)ws; ws += (size_t)Mc * HF * 2; // 25.6 MB
    unsigned short* Wb = (unsigned short*)ws; ws += 32768 * 2;           // 64 KB
    float* att_perm   = (float*)ws; ws += 128 * sizeof(float);
    float* bias_perm  = (float*)ws; ws += 128 * sizeof(float);
    float* gamma_perm = (float*)ws; ws += 128 * sizeof(float);
    float* beta_perm  = (float*)ws; ws += 128 * sizeof(float);
    int* deg = (int*)ws;         ws += (size_t)Mc * sizeof(int);
    int* offs = (int*)ws;        ws += (size_t)Mc * sizeof(int);
    int* cursor = (int*)ws;      ws += (size_t)Mc * sizeof(int);
    int* partials = (int*)ws;    ws += 512;
    int* csr_src = (int*)ws;     ws += (size_t)Ec * sizeof(int);

    const int nb = (Mc + 1023) / 1024; // 98

    prep_w<<<(Mc + 255) / 256, 256, 0, stream>>>(Wl, Wr, att, bias, gamma, beta,
                                                 Wb, att_perm, bias_perm,
                                                 gamma_perm, beta_perm, deg);
    deg_kernel<<<(Ec / 2 + 255) / 256, 256, 0, stream>>>(ei, deg);
    gemm_hlr_mfma<<<(Mc + 63) / 64, 256, 0, stream>>>(x, Wb, bl, br, hl, hr);

    scan_block<<<nb, 256, 0, stream>>>(deg, offs, partials, Mc);
    add_offsets<<<(Mc + 255) / 256, 256, 0, stream>>>(offs, cursor, partials, Mc);
    scatter_edges<<<(Ec + 255) / 256, 256, 0, stream>>>(ei, cursor, csr_src, Ec);

    gat_fused<<<(Mc + 3) / 4, 256, 0, stream>>>(hl, hr, csr_src, offs, deg,
                                                att_perm, bias_perm, gamma_perm,
                                                beta_perm, out);
}

// Round 3
// 275.755 us; speedup vs baseline: 1.1260x; 1.0052x over previous
//
#include <hip/hip_runtime.h>
#include <hip/hip_fp16.h>
#include <cmath>

// Problem constants (fixed by the reference)
constexpr int Bc = 2;
constexpr int Cc = 128;      // input channels
constexpr int Nc = 50000;
constexpr int Hh = 2;        // heads
constexpr int FHc = 64;      // features per head
constexpr int HF = Hh * FHc; // 128 = concat dim
constexpr int Mc = Bc * Nc;  // 100000 nodes
constexpr int Ec = 800000;   // edges

#define NSLOPE_GAT 0.2f
#define NSLOPE_ACT 0.01f
#define LN_EPS 1e-5f
#define SM_EPS 1e-16f
#define LOG2E 1.4426950408889634f

// h-storage is column-swizzled: c' = (c%16)*8 + c/16  (c = canonical col)
// inverse: c = (c'%8)*16 + c'/8. Head of swizzled col c': (c'&7) >= 4.
// => any aligned group of 4 consecutive swizzled cols (one uint2 of fp16)
//    lies entirely within ONE head: head = parity of the group index c'/4.

typedef __attribute__((ext_vector_type(8))) short short8;
typedef __attribute__((ext_vector_type(4))) float f32x4;
typedef _Float16 half2v __attribute__((ext_vector_type(2)));

__device__ inline unsigned short f2bf(float f) {
    union { float f; unsigned int i; } v; v.f = f;
    unsigned int r = v.i + 0x7fffu + ((v.i >> 16) & 1u);
    return (unsigned short)(r >> 16);
}

#if __has_builtin(__builtin_amdgcn_exp2f)
#define EXP2(x) __builtin_amdgcn_exp2f(x)
#else
#define EXP2(x) __expf((x) * 0.6931471805599453f)
#endif

#if __has_builtin(__builtin_amdgcn_fdot2)
#define FDOT2(a, b, c) __builtin_amdgcn_fdot2((a), (b), (c), false)
#else
__device__ inline float FDOT2(half2v a, half2v b, float c) {
    return fmaf((float)a[0], (float)b[0], fmaf((float)a[1], (float)b[1], c));
}
#endif

// One v_add_f32 + DPP row-rotate step (rows of 16 lanes, all lanes active).
template <int CTRL>
__device__ inline float dpp_add_step(float x) {
    int y = __builtin_amdgcn_update_dpp(0, __builtin_bit_cast(int, x),
                                        CTRL, 0xF, 0xF, false);
    return x + __builtin_bit_cast(float, y);
}
// Full-row (16-lane) sum via row_ror 1,2,4,8 — every lane ends with the total.
__device__ inline float row16_sum(float x) {
    x = dpp_add_step<0x121>(x); // row_ror:1
    x = dpp_add_step<0x122>(x); // row_ror:2
    x = dpp_add_step<0x124>(x); // row_ror:4
    x = dpp_add_step<0x128>(x); // row_ror:8
    return x;
}

// ---------------- K0: W -> B-fragment order (bf16), perm att(fp16)/bias/
//                      gamma/beta, zero deg ---------------------------------
// Wb index = ((((mat*8+nt)*4+s)*64)+l)*8 + j ; holds W[k=32s+8*(l>>4)+j][n=16nt+(l&15)]
__global__ __launch_bounds__(256) void prep_w(
    const float* __restrict__ Wl, const float* __restrict__ Wr,
    const float* __restrict__ att, const float* __restrict__ bias,
    const float* __restrict__ gamma, const float* __restrict__ beta,
    unsigned short* __restrict__ Wb, _Float16* __restrict__ att_h,
    float* __restrict__ bias_perm, float* __restrict__ gamma_perm,
    float* __restrict__ beta_perm, int* __restrict__ deg)
{
    int i = blockIdx.x * 256 + threadIdx.x;
    if (i < Mc) deg[i] = 0;
    if (blockIdx.x == 0 && threadIdx.x < 128) {
        int cp = threadIdx.x;
        int c = (cp & 7) * 16 + (cp >> 3);          // canonical col of swizzled cp
        att_h[cp]      = (_Float16)(att[c] * LOG2E); // pre-scale for exp2
        bias_perm[cp]  = bias[c];
        gamma_perm[cp] = gamma[c];
        beta_perm[cp]  = beta[c];
    }
    if (i >= 32768) return;
    int j = i & 7, l = (i >> 3) & 63, s = (i >> 9) & 3, nt = (i >> 11) & 7, mat = (i >> 14) & 1;
    int q = l >> 4, n15 = l & 15;
    int k = 32 * s + 8 * q + j;
    int n = 16 * nt + n15;
    const float* W = mat ? Wr : Wl;
    Wb[i] = f2bf(W[k * HF + n]);
}

// ---------------- degree count (standalone: no barrier behind the atomics) --
__global__ __launch_bounds__(256) void deg_kernel(const int* __restrict__ ei,
                                                  int* __restrict__ deg) {
    int g = blockIdx.x * 256 + threadIdx.x;
    int e = g * 4;
    if (e + 3 < Ec) {
        int4 dd = *(const int4*)(ei + Ec + e);
        atomicAdd(&deg[dd.x], 1);
        atomicAdd(&deg[dd.y], 1);
        atomicAdd(&deg[dd.z], 1);
        atomicAdd(&deg[dd.w], 1);
    } else {
        for (int k = e; k < Ec; ++k) atomicAdd(&deg[ei[Ec + k]], 1);
    }
}

// ---------------- K1: MFMA GEMM -> hl, hr fp16, swizzled cols ---------------
// 64-row M-tile, 4 waves. Wave w owns matrix (w>>1), nt columns 4*(w&1)..+3:
// its 16 B-fragments load from global ONCE into 64 VGPRs. A-tile staged as
// bf16 [row][k] with byte ^= (row&7)<<4 XOR swizzle: conflict-free b128 reads.
__global__ __launch_bounds__(256, 3) void gemm_hlr_mfma(
    const float* __restrict__ x,
    const unsigned short* __restrict__ Wb,
    const float* __restrict__ bl, const float* __restrict__ br,
    unsigned short* __restrict__ hl, unsigned short* __restrict__ hr)
{
    __shared__ unsigned char As[64 * 256]; // 16 KB: [row][2*k] bf16, swizzled
    const int tid = threadIdx.x;
    const int r0 = blockIdx.x * 64;
    const int l = tid & 63, w = tid >> 6;
    const int m15 = l & 15, q = l >> 4;

    // --- B fragments: 16 per wave, global->VGPR once (L2-hot, 64 KB total)
    const int matw = w >> 1, ntb = 4 * (w & 1);
    const short8* __restrict__ WB = (const short8*)Wb;
    short8 bfrag[4][4]; // [i = nt offset][s = k-step]
    #pragma unroll
    for (int i = 0; i < 4; ++i)
        #pragma unroll
        for (int s = 0; s < 4; ++s)
            bfrag[i][s] = WB[(((matw * 8 + ntb + i) * 4 + s) * 64) + l];

    // --- stage A: lane = row, 4 channels/thread/pass, dword loads
    {
        const int lrow = tid & 63;          // local row
        const int cg   = (tid >> 6) * 4;    // channel group base
        const int grow = r0 + lrow;
        const unsigned int swz = (unsigned)((lrow & 7) << 4);
        const bool valid = grow < Mc;
        int b = 0, n = grow;
        if (n >= Nc) { b = 1; n -= Nc; }
        const float* xb = x + (size_t)(b * Cc) * Nc + n;
        #pragma unroll
        for (int p = 0; p < 8; ++p) {
            int c = cg + 16 * p;
            float v0 = 0.f, v1 = 0.f, v2 = 0.f, v3 = 0.f;
            if (valid) {
                const float* xp = xb + (size_t)c * Nc;
                v0 = xp[0];
                v1 = xp[Nc];
                v2 = xp[2 * (size_t)Nc];
                v3 = xp[3 * (size_t)Nc];
            }
            unsigned int d0 = (unsigned)f2bf(v0) | ((unsigned)f2bf(v1) << 16);
            unsigned int d1 = (unsigned)f2bf(v2) | ((unsigned)f2bf(v3) << 16);
            unsigned int off = (unsigned)lrow * 256 + (((unsigned)(c * 2)) ^ swz);
            *(uint2*)(As + off) = make_uint2(d0, d1);
        }
    }
    __syncthreads();

    // --- bias (canonical col = 16*nt + m15) and output base
    const float* bsrc = matw ? br : bl;
    unsigned short* __restrict__ hdst = matw ? hr : hl;
    float bv[4];
    #pragma unroll
    for (int i = 0; i < 4; ++i) bv[i] = bsrc[16 * (ntb + i) + m15];

    const unsigned int rswz = (unsigned)((m15 & 7) << 4);
    #pragma unroll
    for (int mt = 0; mt < 4; ++mt) {
        short8 af[4];
        #pragma unroll
        for (int s = 0; s < 4; ++s) {
            unsigned int off = (unsigned)(16 * mt + m15) * 256 +
                               (((unsigned)(64 * s + 16 * q)) ^ rswz);
            af[s] = *(const short8*)(As + off);
        }
        f32x4 acc[4];
        #pragma unroll
        for (int i = 0; i < 4; ++i) acc[i] = (f32x4)(0.f);
        #pragma unroll
        for (int s = 0; s < 4; ++s)
            #pragma unroll
            for (int i = 0; i < 4; ++i)
                acc[i] = __builtin_amdgcn_mfma_f32_16x16x32_bf16(af[s], bfrag[i][s], acc[i], 0, 0, 0);

        // D: row = 4q+reg (tile-local), canonical col = 16*(ntb+i)+m15
        // swizzled col' = m15*8 + ntb + i  ->  uint2 (4 fp16) per row
        #pragma unroll
        for (int reg = 0; reg < 4; ++reg) {
            int rD = r0 + 16 * mt + 4 * q + reg;
            if (rD < Mc) {
                half2v hlo = { (_Float16)(acc[0][reg] + bv[0]),
                               (_Float16)(acc[1][reg] + bv[1]) };
                half2v hhi = { (_Float16)(acc[2][reg] + bv[2]),
                               (_Float16)(acc[3][reg] + bv[3]) };
                *(uint2*)(hdst + (size_t)rD * HF + m15 * 8 + ntb) =
                    make_uint2(__builtin_bit_cast(unsigned int, hlo),
                               __builtin_bit_cast(unsigned int, hhi));
            }
        }
    }
}

// ---------------- CSR build -------------------------------------------------
__global__ __launch_bounds__(256) void scan_block(const int* __restrict__ deg,
                                                  int* __restrict__ offs,
                                                  int* __restrict__ partials, int M)
{
    __shared__ int sdata[256];
    const int base = blockIdx.x * 1024;
    const int tid = threadIdx.x;
    int v[4];
    int tsum = 0;
    #pragma unroll
    for (int j = 0; j < 4; ++j) {
        int idx = base + tid * 4 + j;
        v[j] = (idx < M) ? deg[idx] : 0;
        tsum += v[j];
    }
    sdata[tid] = tsum;
    __syncthreads();
    for (int off = 1; off < 256; off <<= 1) {
        int xv = (tid >= off) ? sdata[tid - off] : 0;
        __syncthreads();
        sdata[tid] += xv;
        __syncthreads();
    }
    int run = sdata[tid] - tsum;
    #pragma unroll
    for (int j = 0; j < 4; ++j) {
        int idx = base + tid * 4 + j;
        if (idx < M) offs[idx] = run;
        run += v[j];
    }
    if (tid == 255) partials[blockIdx.x] = sdata[255]; // RAW block sums
}

// Each block covers idx in [blk*256, blk*256+256) -> one 1024-chunk
// (chunk = blk>>2), so it just needs sum(partials[0..chunk-1]).
__global__ __launch_bounds__(256) void add_offsets(int* __restrict__ offs,
                                                   int* __restrict__ cursor,
                                                   const int* __restrict__ partials,
                                                   int M) {
    __shared__ int sw[4];
    const int chunk = blockIdx.x >> 2;
    const int t = threadIdx.x;
    int v = (t < chunk) ? partials[t] : 0; // chunk <= 97 < 256
    #pragma unroll
    for (int o = 32; o; o >>= 1) v += __shfl_xor(v, o, 64);
    if ((t & 63) == 0) sw[t >> 6] = v;
    __syncthreads();
    int base = sw[0] + sw[1] + sw[2] + sw[3];
    int idx = blockIdx.x * 256 + t;
    if (idx < M) {
        int o = offs[idx] + base;
        offs[idx] = o;
        cursor[idx] = o;
    }
}

__global__ void scatter_edges(const int* __restrict__ ei, int* __restrict__ cursor,
                              int* __restrict__ csr_src, int E) {
    int g = blockIdx.x * 256 + threadIdx.x;
    int e = g * 2;
    if (e + 1 < E) {
        int2 ss = *(const int2*)(ei + e);
        int2 dd = *(const int2*)(ei + E + e);
        int p0 = atomicAdd(&cursor[dd.x], 1);
        csr_src[p0] = ss.x;
        int p1 = atomicAdd(&cursor[dd.y], 1);
        csr_src[p1] = ss.y;
    } else if (e < E) {
        int p = atomicAdd(&cursor[ei[E + e]], 1);
        csr_src[p] = ei[e];
    }
}

// ---------------- K4: fully fused per-node logits+softmax+aggregate+LN ------
// One wave per node, TWO edges per iteration (one per 32-lane half).
// Lane t: half = t>>5 (edge select), i32 = t&31. Lane owns swizzled col
// GROUP g = ((i32&15)<<1)|(i32>>4) -> cols 4g..4g+3, all in head g&1 = i32>>4.
// So each head's 64 features live in ONE contiguous 16-lane DPP row: the
// per-head dot reduction is 4 v_add_f32+row_ror DPP ops -- no LDS, no
// shuffles in the inner loop. fp16 storage: packed v_pk_add/mul/max_f16 +
// v_dot2_f32_f16 for the dot; v_fma_mix_f32 for the f32 accumulate.
__global__ __launch_bounds__(256) void gat_fused(
    const unsigned short* __restrict__ hl, const unsigned short* __restrict__ hr,
    const int* __restrict__ csr_src,
    const int* __restrict__ offs, const int* __restrict__ deg,
    const _Float16* __restrict__ att_h, const float* __restrict__ bias_perm,
    const float* __restrict__ gamma_perm, const float* __restrict__ beta_perm,
    float* __restrict__ out)
{
    const int wv = threadIdx.x >> 6;
    const int t  = threadIdx.x & 63;
    const int d  = blockIdx.x * 4 + wv;
    if (d >= Mc) return;
    const int off = __builtin_amdgcn_readfirstlane(offs[d]);
    const int n   = __builtin_amdgcn_readfirstlane(deg[d]);
    const int i32 = t & 31;
    const bool hiHalf = (t >= 32);
    const int g = ((i32 & 15) << 1) | (i32 >> 4); // swizzled col group
    const unsigned int voff = 8u * (unsigned)g;   // byte offset within a 256B row

    const uint2 urr = *(const uint2*)((const char*)hr + (size_t)d * 256 + voff);
    const half2v HR01 = __builtin_bit_cast(half2v, urr.x);
    const half2v HR23 = __builtin_bit_cast(half2v, urr.y);
    const uint2 apu = *(const uint2*)((const char*)att_h + voff);
    const half2v ap01 = __builtin_bit_cast(half2v, apu.x);
    const half2v ap23 = __builtin_bit_cast(half2v, apu.y);
    const half2v slope2 = { (_Float16)NSLOPE_GAT, (_Float16)NSLOPE_GAT };

    float l = 0.f, acc0 = 0.f, acc1 = 0.f, acc2 = 0.f, acc3 = 0.f;
    const char* __restrict__ hlb = (const char*)hl;

    auto load2 = [&](int sa, int sb) -> uint2 {
        int s = hiHalf ? sb : sa;
        return *(const uint2*)(hlb + (((unsigned int)s) << 8) + voff);
    };
    auto compute = [&](uint2 u, bool tailMask) {
        half2v A01 = __builtin_bit_cast(half2v, u.x);
        half2v A23 = __builtin_bit_cast(half2v, u.y);
        half2v z01 = A01 + HR01;
        half2v z23 = A23 + HR23;
        z01 = __builtin_elementwise_max(z01, z01 * slope2); // leaky_relu
        z23 = __builtin_elementwise_max(z23, z23 * slope2);
        float p = FDOT2(z01, ap01, FDOT2(z23, ap23, 0.f));
        p = row16_sum(p);                // per-head dot over the 16-lane row
        float w = EXP2(p);               // att pre-scaled by log2e
        if (tailMask && hiHalf) w = 0.f; // odd-degree tail: high half is a dup
        l += w;
        acc0 = fmaf(w, (float)A01[0], acc0);
        acc1 = fmaf(w, (float)A01[1], acc1);
        acc2 = fmaf(w, (float)A23[0], acc2);
        acc3 = fmaf(w, (float)A23[1], acc3);
    };

    int i = 0;
    for (; i + 4 <= n; i += 4) {
        int s0 = csr_src[off + i];
        int s1 = csr_src[off + i + 1];
        int s2 = csr_src[off + i + 2];
        int s3 = csr_src[off + i + 3];
        uint2 u0 = load2(s0, s1);
        uint2 u1 = load2(s2, s3);
        compute(u0, false);
        compute(u1, false);
    }
    if (i + 2 <= n) {
        int s0 = csr_src[off + i];
        int s1 = csr_src[off + i + 1];
        uint2 u0 = load2(s0, s1);
        compute(u0, false);
        i += 2;
    }
    if (i < n) {
        int s0 = csr_src[off + i];
        uint2 u0 = load2(s0, s0);
        compute(u0, true);
    }

    // merge the two edge-halves (same swizzled cols in both halves)
    l    += __shfl_xor(l, 32, 64);
    acc0 += __shfl_xor(acc0, 32, 64);
    acc1 += __shfl_xor(acc1, 32, 64);
    acc2 += __shfl_xor(acc2, 32, 64);
    acc3 += __shfl_xor(acc3, 32, 64);

    float inv = 1.f / (l + SM_EPS);
    const float4 bp = *(const float4*)(bias_perm + 4 * g);
    float v0 = fmaf(acc0, inv, bp.x);
    float v1 = fmaf(acc1, inv, bp.y);
    float v2 = fmaf(acc2, inv, bp.z);
    float v3 = fmaf(acc3, inv, bp.w);

    // LayerNorm over 128 features: each 32-lane half holds all 128 exactly once
    float sum = (v0 + v1) + (v2 + v3);
    #pragma unroll
    for (int o = 1; o <= 16; o <<= 1) sum += __shfl_xor(sum, o, 64);
    float mu = sum * (1.f / 128.f);
    float d0 = v0 - mu, d1 = v1 - mu, d2 = v2 - mu, d3 = v3 - mu;
    float sq = (d0 * d0 + d1 * d1) + (d2 * d2 + d3 * d3);
    #pragma unroll
    for (int o = 1; o <= 16; o <<= 1) sq += __shfl_xor(sq, o, 64);
    float rstd = rsqrtf(sq * (1.f / 128.f) + LN_EPS);

    const float4 ga = *(const float4*)(gamma_perm + 4 * g);
    const float4 be = *(const float4*)(beta_perm + 4 * g);
    float y0 = fmaf(d0 * rstd, ga.x, be.x);
    float y1 = fmaf(d1 * rstd, ga.y, be.y);
    float y2 = fmaf(d2 * rstd, ga.z, be.z);
    float y3 = fmaf(d3 * rstd, ga.w, be.w);
    y0 = fmaxf(y0, NSLOPE_ACT * y0);
    y1 = fmaxf(y1, NSLOPE_ACT * y1);
    y2 = fmaxf(y2, NSLOPE_ACT * y2);
    y3 = fmaxf(y3, NSLOPE_ACT * y3);

    // canonical col of slot j: c = 64*(g&1) + 16*j + (g>>1)
    if (!hiHalf) {
        const int h = g & 1, m = g >> 1;
        float* op = out + (size_t)d * HF + 64 * h + m;
        op[0]  = y0;
        op[16] = y1;
        op[32] = y2;
        op[48] = y3;
    }
}

// ---------------- launch ----------------
extern "C" void kernel_launch(void* const* d_in, const int* in_sizes, int n_in,
                              void* d_out, int out_size, void* d_ws, size_t ws_size,
                              hipStream_t stream) {
    const float* x     = (const float*)d_in[0];
    const int*   ei    = (const int*)d_in[1];
    const float* Wl    = (const float*)d_in[2];
    const float* bl    = (const float*)d_in[3];
    const float* Wr    = (const float*)d_in[4];
    const float* br    = (const float*)d_in[5];
    const float* att   = (const float*)d_in[6];
    const float* bias  = (const float*)d_in[7];
    const float* gamma = (const float*)d_in[8];
    const float* beta  = (const float*)d_in[9];
    float* out = (float*)d_out;

    char* ws = (char*)d_ws;
    unsigned short* hl = (unsigned short*)ws; ws += (size_t)Mc * HF * 2; // 25.6 MB (fp16)
    unsigned short* hr = (unsigned short*)ws; ws += (size_t)Mc * HF * 2; // 25.6 MB (fp16)
    unsigned short* Wb = (unsigned short*)ws; ws += 32768 * 2;           // 64 KB (bf16)
    _Float16* att_h   = (_Float16*)ws; ws += 512;                        // 128 fp16 (+pad)
    float* bias_perm  = (float*)ws; ws += 128 * sizeof(float);
    float* gamma_perm = (float*)ws; ws += 128 * sizeof(float);
    float* beta_perm  = (float*)ws; ws += 128 * sizeof(float);
    int* deg = (int*)ws;         ws += (size_t)Mc * sizeof(int);
    int* offs = (int*)ws;        ws += (size_t)Mc * sizeof(int);
    int* cursor = (int*)ws;      ws += (size_t)Mc * sizeof(int);
    int* partials = (int*)ws;    ws += 512;
    int* csr_src = (int*)ws;     ws += (size_t)Ec * sizeof(int);

    const int nb = (Mc + 1023) / 1024; // 98

    prep_w<<<(Mc + 255) / 256, 256, 0, stream>>>(Wl, Wr, att, bias, gamma, beta,
                                                 Wb, att_h, bias_perm,
                                                 gamma_perm, beta_perm, deg);
    deg_kernel<<<(Ec / 4 + 255) / 256, 256, 0, stream>>>(ei, deg);
    gemm_hlr_mfma<<<(Mc + 63) / 64, 256, 0, stream>>>(x, Wb, bl, br, hl, hr);

    scan_block<<<nb, 256, 0, stream>>>(deg, offs, partials, Mc);
    add_offsets<<<(Mc + 255) / 256, 256, 0, stream>>>(offs, cursor, partials, Mc);
    scatter_edges<<<(Ec / 2 + 255) / 256, 256, 0, stream>>>(ei, cursor, csr_src, Ec);

    gat_fused<<<(Mc + 3) / 4, 256, 0, stream>>>(hl, hr, csr_src, offs, deg,
                                                att_h, bias_perm, gamma_perm,
                                                beta_perm, out);
}

// Round 4
// 226.778 us; speedup vs baseline: 1.3692x; 1.2160x over previous
//
#include <hip/hip_runtime.h>
#include <hip/hip_fp16.h>
#include <cmath>

// Problem constants (fixed by the reference)
constexpr int Bc = 2;
constexpr int Cc = 128;      // input channels
constexpr int Nc = 50000;
constexpr int Hh = 2;        // heads
constexpr int FHc = 64;      // features per head
constexpr int HF = Hh * FHc; // 128 = concat dim
constexpr int Mc = Bc * Nc;  // 100000 nodes
constexpr int Ec = 800000;   // edges

// CSR counting-sort geometry
constexpr int PBLK = 64;                   // partition blocks (passes A/C)
constexpr int CHUNK = Ec / PBLK;           // 12500 edges per partition
constexpr int KBKT = (Mc + 255) / 256;     // 391 buckets of 256 dst nodes

#define NSLOPE_GAT 0.2f
#define NSLOPE_ACT 0.01f
#define LN_EPS 1e-5f
#define SM_EPS 1e-16f
#define LOG2E 1.4426950408889634f

// h-storage is column-swizzled: c' = (c%16)*8 + c/16  (c = canonical col)
// inverse: c = (c'%8)*16 + c'/8. Head of swizzled col c': (c'&7) >= 4.
// => any aligned group of 4 consecutive swizzled cols (one uint2 of fp16)
//    lies entirely within ONE head: head = parity of the group index c'/4.

typedef __attribute__((ext_vector_type(8))) short short8;
typedef __attribute__((ext_vector_type(4))) float f32x4;
typedef _Float16 half2v __attribute__((ext_vector_type(2)));

__device__ inline unsigned short f2bf(float f) {
    union { float f; unsigned int i; } v; v.f = f;
    unsigned int r = v.i + 0x7fffu + ((v.i >> 16) & 1u);
    return (unsigned short)(r >> 16);
}

#if __has_builtin(__builtin_amdgcn_exp2f)
#define EXP2(x) __builtin_amdgcn_exp2f(x)
#else
#define EXP2(x) __expf((x) * 0.6931471805599453f)
#endif

#if __has_builtin(__builtin_amdgcn_fdot2)
#define FDOT2(a, b, c) __builtin_amdgcn_fdot2((a), (b), (c), false)
#else
__device__ inline float FDOT2(half2v a, half2v b, float c) {
    return fmaf((float)a[0], (float)b[0], fmaf((float)a[1], (float)b[1], c));
}
#endif

// One v_add_f32 + DPP row-rotate step (rows of 16 lanes, all lanes active).
template <int CTRL>
__device__ inline float dpp_add_step(float x) {
    int y = __builtin_amdgcn_update_dpp(0, __builtin_bit_cast(int, x),
                                        CTRL, 0xF, 0xF, false);
    return x + __builtin_bit_cast(float, y);
}
// Full-row (16-lane) sum via row_ror 1,2,4,8 — every lane ends with the total.
__device__ inline float row16_sum(float x) {
    x = dpp_add_step<0x121>(x); // row_ror:1
    x = dpp_add_step<0x122>(x); // row_ror:2
    x = dpp_add_step<0x124>(x); // row_ror:4
    x = dpp_add_step<0x128>(x); // row_ror:8
    return x;
}

// ---------------- K0: W -> B-fragment order (bf16), perm att(fp16)/bias/
//                      gamma/beta ------------------------------------------
// Wb index = ((((mat*8+nt)*4+s)*64)+l)*8 + j ; holds W[k=32s+8*(l>>4)+j][n=16nt+(l&15)]
__global__ __launch_bounds__(256) void prep_w(
    const float* __restrict__ Wl, const float* __restrict__ Wr,
    const float* __restrict__ att, const float* __restrict__ bias,
    const float* __restrict__ gamma, const float* __restrict__ beta,
    unsigned short* __restrict__ Wb, _Float16* __restrict__ att_h,
    float* __restrict__ bias_perm, float* __restrict__ gamma_perm,
    float* __restrict__ beta_perm)
{
    int i = blockIdx.x * 256 + threadIdx.x;
    if (blockIdx.x == 0 && threadIdx.x < 128) {
        int cp = threadIdx.x;
        int c = (cp & 7) * 16 + (cp >> 3);          // canonical col of swizzled cp
        att_h[cp]      = (_Float16)(att[c] * LOG2E); // pre-scale for exp2
        bias_perm[cp]  = bias[c];
        gamma_perm[cp] = gamma[c];
        beta_perm[cp]  = beta[c];
    }
    if (i >= 32768) return;
    int j = i & 7, l = (i >> 3) & 63, s = (i >> 9) & 3, nt = (i >> 11) & 7, mat = (i >> 14) & 1;
    int q = l >> 4, n15 = l & 15;
    int k = 32 * s + 8 * q + j;
    int n = 16 * nt + n15;
    const float* W = mat ? Wr : Wl;
    Wb[i] = f2bf(W[k * HF + n]);
}

// ---------------- K1: MFMA GEMM -> hl, hr fp16, swizzled cols ---------------
// 64-row M-tile, 4 waves. Wave w owns matrix (w>>1), nt columns 4*(w&1)..+3:
// its 16 B-fragments load from global ONCE into 64 VGPRs. A-tile staged as
// bf16 [row][k] with byte ^= (row&7)<<4 XOR swizzle: conflict-free b128 reads.
__global__ __launch_bounds__(256, 3) void gemm_hlr_mfma(
    const float* __restrict__ x,
    const unsigned short* __restrict__ Wb,
    const float* __restrict__ bl, const float* __restrict__ br,
    unsigned short* __restrict__ hl, unsigned short* __restrict__ hr)
{
    __shared__ unsigned char As[64 * 256]; // 16 KB: [row][2*k] bf16, swizzled
    const int tid = threadIdx.x;
    const int r0 = blockIdx.x * 64;
    const int l = tid & 63, w = tid >> 6;
    const int m15 = l & 15, q = l >> 4;

    // --- B fragments: 16 per wave, global->VGPR once (L2-hot, 64 KB total)
    const int matw = w >> 1, ntb = 4 * (w & 1);
    const short8* __restrict__ WB = (const short8*)Wb;
    short8 bfrag[4][4]; // [i = nt offset][s = k-step]
    #pragma unroll
    for (int i = 0; i < 4; ++i)
        #pragma unroll
        for (int s = 0; s < 4; ++s)
            bfrag[i][s] = WB[(((matw * 8 + ntb + i) * 4 + s) * 64) + l];

    // --- stage A: lane = row, 4 channels/thread/pass, dword loads
    {
        const int lrow = tid & 63;          // local row
        const int cg   = (tid >> 6) * 4;    // channel group base
        const int grow = r0 + lrow;
        const unsigned int swz = (unsigned)((lrow & 7) << 4);
        const bool valid = grow < Mc;
        int b = 0, n = grow;
        if (n >= Nc) { b = 1; n -= Nc; }
        const float* xb = x + (size_t)(b * Cc) * Nc + n;
        #pragma unroll
        for (int p = 0; p < 8; ++p) {
            int c = cg + 16 * p;
            float v0 = 0.f, v1 = 0.f, v2 = 0.f, v3 = 0.f;
            if (valid) {
                const float* xp = xb + (size_t)c * Nc;
                v0 = xp[0];
                v1 = xp[Nc];
                v2 = xp[2 * (size_t)Nc];
                v3 = xp[3 * (size_t)Nc];
            }
            unsigned int d0 = (unsigned)f2bf(v0) | ((unsigned)f2bf(v1) << 16);
            unsigned int d1 = (unsigned)f2bf(v2) | ((unsigned)f2bf(v3) << 16);
            unsigned int off = (unsigned)lrow * 256 + (((unsigned)(c * 2)) ^ swz);
            *(uint2*)(As + off) = make_uint2(d0, d1);
        }
    }
    __syncthreads();

    // --- bias (canonical col = 16*nt + m15) and output base
    const float* bsrc = matw ? br : bl;
    unsigned short* __restrict__ hdst = matw ? hr : hl;
    float bv[4];
    #pragma unroll
    for (int i = 0; i < 4; ++i) bv[i] = bsrc[16 * (ntb + i) + m15];

    const unsigned int rswz = (unsigned)((m15 & 7) << 4);
    #pragma unroll
    for (int mt = 0; mt < 4; ++mt) {
        short8 af[4];
        #pragma unroll
        for (int s = 0; s < 4; ++s) {
            unsigned int off = (unsigned)(16 * mt + m15) * 256 +
                               (((unsigned)(64 * s + 16 * q)) ^ rswz);
            af[s] = *(const short8*)(As + off);
        }
        f32x4 acc[4];
        #pragma unroll
        for (int i = 0; i < 4; ++i) acc[i] = (f32x4)(0.f);
        #pragma unroll
        for (int s = 0; s < 4; ++s)
            #pragma unroll
            for (int i = 0; i < 4; ++i)
                acc[i] = __builtin_amdgcn_mfma_f32_16x16x32_bf16(af[s], bfrag[i][s], acc[i], 0, 0, 0);

        // D: row = 4q+reg (tile-local), canonical col = 16*(ntb+i)+m15
        // swizzled col' = m15*8 + ntb + i  ->  uint2 (4 fp16) per row
        #pragma unroll
        for (int reg = 0; reg < 4; ++reg) {
            int rD = r0 + 16 * mt + 4 * q + reg;
            if (rD < Mc) {
                half2v hlo = { (_Float16)(acc[0][reg] + bv[0]),
                               (_Float16)(acc[1][reg] + bv[1]) };
                half2v hhi = { (_Float16)(acc[2][reg] + bv[2]),
                               (_Float16)(acc[3][reg] + bv[3]) };
                *(uint2*)(hdst + (size_t)rD * HF + m15 * 8 + ntb) =
                    make_uint2(__builtin_bit_cast(unsigned int, hlo),
                               __builtin_bit_cast(unsigned int, hhi));
            }
        }
    }
}

// ---------------- CSR build: 2-level counting sort, ZERO global atomics -----
// Pass A: per-partition bucket histogram (LDS atomics only).
__global__ __launch_bounds__(256) void bucket_hist(const int* __restrict__ ei,
                                                   int* __restrict__ counts)
{
    __shared__ int hist[KBKT];
    const int p = blockIdx.x, tid = threadIdx.x;
    for (int k = tid; k < KBKT; k += 256) hist[k] = 0;
    __syncthreads();
    const int4* dsts = (const int4*)(ei + Ec + p * CHUNK);
    for (int i = tid; i < CHUNK / 4; i += 256) {
        int4 d = dsts[i];
        atomicAdd(&hist[d.x >> 8], 1);
        atomicAdd(&hist[d.y >> 8], 1);
        atomicAdd(&hist[d.z >> 8], 1);
        atomicAdd(&hist[d.w >> 8], 1);
    }
    __syncthreads();
    for (int k = tid; k < KBKT; k += 256) counts[p * KBKT + k] = hist[k];
}

// Pass B: single block. Column-scan counts[p][k] -> offmat[p][k] (each
// partition's private window inside bucket k) + bucketBase[k] (K+1 entries).
__global__ __launch_bounds__(512) void bucket_scan(const int* __restrict__ counts,
                                                   int* __restrict__ offmat,
                                                   int* __restrict__ bucketBase)
{
    __shared__ int cs[512];
    const int k = threadIdx.x;
    int total = 0;
    if (k < KBKT)
        for (int p = 0; p < PBLK; ++p) total += counts[p * KBKT + k]; // coalesced
    cs[k] = total;
    __syncthreads();
    for (int off = 1; off < 512; off <<= 1) {
        int v = (k >= off) ? cs[k - off] : 0;
        __syncthreads();
        cs[k] += v;
        __syncthreads();
    }
    int base = cs[k] - total; // exclusive
    if (k <= KBKT) bucketBase[k] = base; // k==KBKT gets Ec
    if (k < KBKT) {
        int run = base;
        for (int p = 0; p < PBLK; ++p) {
            offmat[p * KBKT + k] = run;
            run += counts[p * KBKT + k];
        }
    }
}

// Pass C: partition p writes its edges into its private contiguous window of
// each bucket region (rank via LDS atomics). pairs[] entry = (src<<8)|dstLocal.
__global__ __launch_bounds__(256) void bucket_scatter(const int* __restrict__ ei,
                                                      const int* __restrict__ offmat,
                                                      unsigned int* __restrict__ pairs)
{
    __shared__ int cur[KBKT];
    const int p = blockIdx.x, tid = threadIdx.x;
    for (int k = tid; k < KBKT; k += 256) cur[k] = offmat[p * KBKT + k];
    __syncthreads();
    const int4* srcs = (const int4*)(ei + p * CHUNK);
    const int4* dsts = (const int4*)(ei + Ec + p * CHUNK);
    for (int i = tid; i < CHUNK / 4; i += 256) {
        int4 s = srcs[i];
        int4 d = dsts[i];
        int p0 = atomicAdd(&cur[d.x >> 8], 1);
        pairs[p0] = ((unsigned)s.x << 8) | (unsigned)(d.x & 255);
        int p1 = atomicAdd(&cur[d.y >> 8], 1);
        pairs[p1] = ((unsigned)s.y << 8) | (unsigned)(d.y & 255);
        int p2 = atomicAdd(&cur[d.z >> 8], 1);
        pairs[p2] = ((unsigned)s.z << 8) | (unsigned)(d.z & 255);
        int p3 = atomicAdd(&cur[d.w >> 8], 1);
        pairs[p3] = ((unsigned)s.w << 8) | (unsigned)(d.w & 255);
    }
}

// Pass D: one block per bucket. Local node histogram + scan -> offs/deg
// (replaces deg_kernel + scan kernels), then place edges -> csr_src.
__global__ __launch_bounds__(256) void bucket_csr(const unsigned int* __restrict__ pairs,
                                                  const int* __restrict__ bucketBase,
                                                  int* __restrict__ offs,
                                                  int* __restrict__ deg,
                                                  int* __restrict__ csr_src)
{
    __shared__ int cnt[256];
    __shared__ int scn[256];
    __shared__ int cur[256];
    const int b = blockIdx.x, tid = threadIdx.x;
    const int base = bucketBase[b];
    const int ecnt = bucketBase[b + 1] - base;
    cnt[tid] = 0;
    __syncthreads();
    for (int i = tid; i < ecnt; i += 256)
        atomicAdd(&cnt[pairs[base + i] & 255u], 1);
    __syncthreads();
    int c = cnt[tid];
    scn[tid] = c;
    __syncthreads();
    for (int off = 1; off < 256; off <<= 1) {
        int v = (tid >= off) ? scn[tid - off] : 0;
        __syncthreads();
        scn[tid] += v;
        __syncthreads();
    }
    int excl = scn[tid] - c;
    int node = (b << 8) + tid;
    if (node < Mc) {
        offs[node] = base + excl;
        deg[node] = c;
    }
    cur[tid] = base + excl;
    __syncthreads();
    for (int i = tid; i < ecnt; i += 256) {
        unsigned pr = pairs[base + i];
        int pos = atomicAdd(&cur[pr & 255u], 1);
        csr_src[pos] = (int)(pr >> 8);
    }
}

// ---------------- K4: fully fused per-node logits+softmax+aggregate+LN ------
// One wave per node, TWO edges per iteration (one per 32-lane half).
// Lane t: half = t>>5 (edge select), i32 = t&31. Lane owns swizzled col
// GROUP g = ((i32&15)<<1)|(i32>>4) -> cols 4g..4g+3, all in head g&1 = i32>>4.
// So each head's 64 features live in ONE contiguous 16-lane DPP row: the
// per-head dot reduction is 4 v_add_f32+row_ror DPP ops -- no LDS, no
// shuffles in the inner loop. fp16 storage: packed v_pk_add/mul/max_f16 +
// v_dot2_f32_f16 for the dot; v_fma_mix_f32 for the f32 accumulate.
__global__ __launch_bounds__(256) void gat_fused(
    const unsigned short* __restrict__ hl, const unsigned short* __restrict__ hr,
    const int* __restrict__ csr_src,
    const int* __restrict__ offs, const int* __restrict__ deg,
    const _Float16* __restrict__ att_h, const float* __restrict__ bias_perm,
    const float* __restrict__ gamma_perm, const float* __restrict__ beta_perm,
    float* __restrict__ out)
{
    const int wv = threadIdx.x >> 6;
    const int t  = threadIdx.x & 63;
    const int d  = blockIdx.x * 4 + wv;
    if (d >= Mc) return;
    const int off = __builtin_amdgcn_readfirstlane(offs[d]);
    const int n   = __builtin_amdgcn_readfirstlane(deg[d]);
    const int i32 = t & 31;
    const bool hiHalf = (t >= 32);
    const int g = ((i32 & 15) << 1) | (i32 >> 4); // swizzled col group
    const unsigned int voff = 8u * (unsigned)g;   // byte offset within a 256B row

    const uint2 urr = *(const uint2*)((const char*)hr + (size_t)d * 256 + voff);
    const half2v HR01 = __builtin_bit_cast(half2v, urr.x);
    const half2v HR23 = __builtin_bit_cast(half2v, urr.y);
    const uint2 apu = *(const uint2*)((const char*)att_h + voff);
    const half2v ap01 = __builtin_bit_cast(half2v, apu.x);
    const half2v ap23 = __builtin_bit_cast(half2v, apu.y);
    const half2v slope2 = { (_Float16)NSLOPE_GAT, (_Float16)NSLOPE_GAT };

    float l = 0.f, acc0 = 0.f, acc1 = 0.f, acc2 = 0.f, acc3 = 0.f;
    const char* __restrict__ hlb = (const char*)hl;

    auto load2 = [&](int sa, int sb) -> uint2 {
        int s = hiHalf ? sb : sa;
        return *(const uint2*)(hlb + (((unsigned int)s) << 8) + voff);
    };
    auto compute = [&](uint2 u, bool tailMask) {
        half2v A01 = __builtin_bit_cast(half2v, u.x);
        half2v A23 = __builtin_bit_cast(half2v, u.y);
        half2v z01 = A01 + HR01;
        half2v z23 = A23 + HR23;
        z01 = __builtin_elementwise_max(z01, z01 * slope2); // leaky_relu
        z23 = __builtin_elementwise_max(z23, z23 * slope2);
        float p = FDOT2(z01, ap01, FDOT2(z23, ap23, 0.f));
        p = row16_sum(p);                // per-head dot over the 16-lane row
        float w = EXP2(p);               // att pre-scaled by log2e
        if (tailMask && hiHalf) w = 0.f; // odd-degree tail: high half is a dup
        l += w;
        acc0 = fmaf(w, (float)A01[0], acc0);
        acc1 = fmaf(w, (float)A01[1], acc1);
        acc2 = fmaf(w, (float)A23[0], acc2);
        acc3 = fmaf(w, (float)A23[1], acc3);
    };

    int i = 0;
    for (; i + 4 <= n; i += 4) {
        int s0 = csr_src[off + i];
        int s1 = csr_src[off + i + 1];
        int s2 = csr_src[off + i + 2];
        int s3 = csr_src[off + i + 3];
        uint2 u0 = load2(s0, s1);
        uint2 u1 = load2(s2, s3);
        compute(u0, false);
        compute(u1, false);
    }
    if (i + 2 <= n) {
        int s0 = csr_src[off + i];
        int s1 = csr_src[off + i + 1];
        uint2 u0 = load2(s0, s1);
        compute(u0, false);
        i += 2;
    }
    if (i < n) {
        int s0 = csr_src[off + i];
        uint2 u0 = load2(s0, s0);
        compute(u0, true);
    }

    // merge the two edge-halves (same swizzled cols in both halves)
    l    += __shfl_xor(l, 32, 64);
    acc0 += __shfl_xor(acc0, 32, 64);
    acc1 += __shfl_xor(acc1, 32, 64);
    acc2 += __shfl_xor(acc2, 32, 64);
    acc3 += __shfl_xor(acc3, 32, 64);

    float inv = 1.f / (l + SM_EPS);
    const float4 bp = *(const float4*)(bias_perm + 4 * g);
    float v0 = fmaf(acc0, inv, bp.x);
    float v1 = fmaf(acc1, inv, bp.y);
    float v2 = fmaf(acc2, inv, bp.z);
    float v3 = fmaf(acc3, inv, bp.w);

    // LayerNorm over 128 features: each 32-lane half holds all 128 exactly once
    float sum = (v0 + v1) + (v2 + v3);
    #pragma unroll
    for (int o = 1; o <= 16; o <<= 1) sum += __shfl_xor(sum, o, 64);
    float mu = sum * (1.f / 128.f);
    float d0 = v0 - mu, d1 = v1 - mu, d2 = v2 - mu, d3 = v3 - mu;
    float sq = (d0 * d0 + d1 * d1) + (d2 * d2 + d3 * d3);
    #pragma unroll
    for (int o = 1; o <= 16; o <<= 1) sq += __shfl_xor(sq, o, 64);
    float rstd = rsqrtf(sq * (1.f / 128.f) + LN_EPS);

    const float4 ga = *(const float4*)(gamma_perm + 4 * g);
    const float4 be = *(const float4*)(beta_perm + 4 * g);
    float y0 = fmaf(d0 * rstd, ga.x, be.x);
    float y1 = fmaf(d1 * rstd, ga.y, be.y);
    float y2 = fmaf(d2 * rstd, ga.z, be.z);
    float y3 = fmaf(d3 * rstd, ga.w, be.w);
    y0 = fmaxf(y0, NSLOPE_ACT * y0);
    y1 = fmaxf(y1, NSLOPE_ACT * y1);
    y2 = fmaxf(y2, NSLOPE_ACT * y2);
    y3 = fmaxf(y3, NSLOPE_ACT * y3);

    // canonical col of slot j: c = 64*(g&1) + 16*j + (g>>1)
    if (!hiHalf) {
        const int h = g & 1, m = g >> 1;
        float* op = out + (size_t)d * HF + 64 * h + m;
        op[0]  = y0;
        op[16] = y1;
        op[32] = y2;
        op[48] = y3;
    }
}

// ---------------- launch ----------------
extern "C" void kernel_launch(void* const* d_in, const int* in_sizes, int n_in,
                              void* d_out, int out_size, void* d_ws, size_t ws_size,
                              hipStream_t stream) {
    const float* x     = (const float*)d_in[0];
    const int*   ei    = (const int*)d_in[1];
    const float* Wl    = (const float*)d_in[2];
    const float* bl    = (const float*)d_in[3];
    const float* Wr    = (const float*)d_in[4];
    const float* br    = (const float*)d_in[5];
    const float* att   = (const float*)d_in[6];
    const float* bias  = (const float*)d_in[7];
    const float* gamma = (const float*)d_in[8];
    const float* beta  = (const float*)d_in[9];
    float* out = (float*)d_out;

    char* ws = (char*)d_ws;
    unsigned short* hl = (unsigned short*)ws; ws += (size_t)Mc * HF * 2; // 25.6 MB (fp16)
    unsigned short* hr = (unsigned short*)ws; ws += (size_t)Mc * HF * 2; // 25.6 MB (fp16)
    unsigned short* Wb = (unsigned short*)ws; ws += 32768 * 2;           // 64 KB (bf16)
    _Float16* att_h   = (_Float16*)ws; ws += 512;                        // 128 fp16 (+pad)
    float* bias_perm  = (float*)ws; ws += 128 * sizeof(float);
    float* gamma_perm = (float*)ws; ws += 128 * sizeof(float);
    float* beta_perm  = (float*)ws; ws += 128 * sizeof(float);
    int* deg = (int*)ws;        ws += (size_t)Mc * sizeof(int);
    int* offs = (int*)ws;       ws += (size_t)Mc * sizeof(int);
    int* counts = (int*)ws;     ws += (size_t)PBLK * KBKT * sizeof(int); // 100 KB
    int* offmat = (int*)ws;     ws += (size_t)PBLK * KBKT * sizeof(int); // 100 KB
    int* bucketBase = (int*)ws; ws += (KBKT + 1 + 63) * sizeof(int);
    unsigned int* pairs = (unsigned int*)ws; ws += (size_t)Ec * sizeof(int); // 3.2 MB
    int* csr_src = (int*)ws;    ws += (size_t)Ec * sizeof(int);              // 3.2 MB

    prep_w<<<128, 256, 0, stream>>>(Wl, Wr, att, bias, gamma, beta,
                                    Wb, att_h, bias_perm, gamma_perm, beta_perm);
    bucket_hist<<<PBLK, 256, 0, stream>>>(ei, counts);
    gemm_hlr_mfma<<<(Mc + 63) / 64, 256, 0, stream>>>(x, Wb, bl, br, hl, hr);
    bucket_scan<<<1, 512, 0, stream>>>(counts, offmat, bucketBase);
    bucket_scatter<<<PBLK, 256, 0, stream>>>(ei, offmat, pairs);
    bucket_csr<<<KBKT, 256, 0, stream>>>(pairs, bucketBase, offs, deg, csr_src);

    gat_fused<<<(Mc + 3) / 4, 256, 0, stream>>>(hl, hr, csr_src, offs, deg,
                                                att_h, bias_perm, gamma_perm,
                                                beta_perm, out);
}